// Round 2
// baseline (1086.772 us; speedup 1.0000x reference)
//
#include <hip/hip_runtime.h>

// Problem constants
#define B_   128
#define T_   512
#define EMB_ 128
#define H_   128
#define G4_  512    // 4*H (one direction's gate count)
#define NG_  1024   // both directions
#define NL_  9
#define MT_  65536  // B*T

typedef __attribute__((ext_vector_type(8))) short short8v;
typedef __attribute__((ext_vector_type(4))) float float4v;

__device__ inline unsigned short f2bf(float f){
  unsigned u = __float_as_uint(f);
  u += 0x7FFFu + ((u >> 16) & 1u);          // round-to-nearest-even
  return (unsigned short)(u >> 16);
}
__device__ inline float bf2f(unsigned short s){
  return __uint_as_float(((unsigned)s) << 16);
}
__device__ inline float sigm(float x){ return 1.f / (1.f + __expf(-x)); }
__device__ inline float tanh_(float x){ return 2.f / (1.f + __expf(-2.f * x)) - 1.f; }

// ---------------------------------------------------------------- K0: weight prep
__global__ void k0_prep(const float* __restrict__ Wf, const float* __restrict__ Wb,
                        const float* __restrict__ bihf, const float* __restrict__ bhhf,
                        const float* __restrict__ bihb, const float* __restrict__ bhhb,
                        unsigned short* __restrict__ Wcat, float* __restrict__ biasc){
  int n = blockIdx.x;          // 0..1023
  int k = threadIdx.x;         // 0..127
  const float* src = (n < G4_) ? (Wf + n * EMB_) : (Wb + (n - G4_) * EMB_);
  Wcat[n * EMB_ + k] = f2bf(src[k]);
  if (k == 0)
    biasc[n] = (n < G4_) ? (bihf[n] + bhhf[n]) : (bihb[n - G4_] + bhhb[n - G4_]);
}

// ---------------------------------------------------------------- K1: embedding gather -> bf16
__global__ void k1_embed(const int* __restrict__ chars, const float* __restrict__ emb,
                         unsigned short* __restrict__ x){
  int i = blockIdx.x * blockDim.x + threadIdx.x;  // 2,097,152 total (each does 4 elems)
  int m = i >> 5, q = i & 31;
  int c = chars[m];
  const float4* e4 = (const float4*)(emb + (long)c * EMB_);
  float4 v = e4[q];
  ushort4 o;
  o.x = f2bf(v.x); o.y = f2bf(v.y); o.z = f2bf(v.z); o.w = f2bf(v.w);
  *(ushort4*)(x + (long)m * EMB_ + q * 4) = o;
}

// ---------------------------------------------------------------- K2: input projection GEMM (MFMA)
// G[m][n] = sum_k x[m][k] * Wcat[n][k] + biasc[n]   (m: B*T, n: 1024 gates, k: 128)
__global__ __launch_bounds__(256) void k2_gemm(const unsigned short* __restrict__ x,
                                               const unsigned short* __restrict__ Wcat,
                                               const float* __restrict__ biasc,
                                               unsigned short* __restrict__ G){
  int w = threadIdx.x >> 6, lane = threadIdx.x & 63;
  int r = lane & 15, kb = (lane >> 4) * 8;
  long arow = (long)(blockIdx.x * 64 + w * 16 + r);
  short8v a[4];
  #pragma unroll
  for (int kf = 0; kf < 4; kf++)
    a[kf] = *(const short8v*)(x + arow * EMB_ + kf * 32 + kb);
  int ncol0 = blockIdx.y * 128;
  float4v acc[8];
  #pragma unroll
  for (int nf = 0; nf < 8; nf++){
    float4v z = {0.f, 0.f, 0.f, 0.f};
    acc[nf] = z;
    int wrow = ncol0 + nf * 16 + r;
    #pragma unroll
    for (int kf = 0; kf < 4; kf++){
      short8v bfrag = *(const short8v*)(Wcat + (long)wrow * EMB_ + kf * 32 + kb);
      acc[nf] = __builtin_amdgcn_mfma_f32_16x16x32_bf16(a[kf], bfrag, acc[nf], 0, 0, 0);
    }
  }
  int crow0 = blockIdx.x * 64 + w * 16 + (lane >> 4) * 4;
  #pragma unroll
  for (int nf = 0; nf < 8; nf++){
    int col = ncol0 + nf * 16 + r;
    float bia = biasc[col];
    #pragma unroll
    for (int reg = 0; reg < 4; reg++)
      G[(long)(crow0 + reg) * NG_ + col] = f2bf(acc[nf][reg] + bia);
  }
}

// ---------------------------------------------------------------- K3: LSTM recurrent scan
// One block per (direction, batch row). Thread j owns gate row j; W_hh row in registers.
__global__ __launch_bounds__(512, 2) void k3_scan(const unsigned short* __restrict__ G,
                                                  const float* __restrict__ Whhf,
                                                  const float* __restrict__ Whhb,
                                                  unsigned short* __restrict__ hs){
  int dir = blockIdx.x >> 7;
  int b   = blockIdx.x & 127;
  int j   = threadIdx.x;   // 0..511
  const float* Whh = dir ? Whhb : Whhf;
  float4 w[32];
  #pragma unroll
  for (int q = 0; q < 32; q++) w[q] = *(const float4*)(Whh + (long)j * H_ + q * 4);
  __shared__ __align__(16) float h[H_];
  __shared__ float g[G4_];
  if (j < H_) h[j] = 0.f;
  float c = 0.f;
  __syncthreads();
  const float4* h4 = (const float4*)h;
  for (int s = 0; s < T_; s++){
    int t = dir ? (T_ - 1 - s) : s;
    long m = (long)b * T_ + t;
    float gv = bf2f(G[m * NG_ + dir * G4_ + j]);
    float a0 = 0.f, a1 = 0.f, a2 = 0.f, a3 = 0.f;
    #pragma unroll
    for (int q = 0; q < 32; q++){
      float4 hv = h4[q];
      a0 = fmaf(w[q].x, hv.x, a0);
      a1 = fmaf(w[q].y, hv.y, a1);
      a2 = fmaf(w[q].z, hv.z, a2);
      a3 = fmaf(w[q].w, hv.w, a3);
    }
    g[j] = gv + (a0 + a1) + (a2 + a3);
    __syncthreads();
    if (j < H_){
      float iv = sigm(g[j]);
      float fv = sigm(g[j + 128]);
      float gg = tanh_(g[j + 256]);
      float ov = sigm(g[j + 384]);
      c = fv * c + iv * gg;
      float hv = ov * tanh_(c);
      h[j] = hv;
      hs[((long)dir * MT_ + m) * H_ + j] = f2bf(hv);
    }
    __syncthreads();
  }
}

// ---------------------------------------------------------------- K4: emissions = [hf,hb] @ Wout^T + bout
#define HSTR 264
__global__ __launch_bounds__(512) void k4_emis(const unsigned short* __restrict__ hs,
                                               const float* __restrict__ Wout,
                                               const float* __restrict__ bout,
                                               float* __restrict__ em){
  __shared__ float hcat[64 * HSTR];
  __shared__ float wo[NL_ * 256];
  int tid = threadIdx.x;
  int m0 = blockIdx.x * 64;
  const unsigned short* hf = hs;
  const unsigned short* hb = hs + (long)MT_ * H_;
  #pragma unroll
  for (int it = 0; it < 8; it++){
    int flat = it * 2048 + tid * 4;       // over 64*256 = 16384 elements
    int r = flat >> 8, u = flat & 255;
    const unsigned short* src = (u < 128) ? (hf + (long)(m0 + r) * H_ + u)
                                          : (hb + (long)(m0 + r) * H_ + (u - 128));
    ushort4 v = *(const ushort4*)src;
    hcat[r * HSTR + u]     = bf2f(v.x);
    hcat[r * HSTR + u + 1] = bf2f(v.y);
    hcat[r * HSTR + u + 2] = bf2f(v.z);
    hcat[r * HSTR + u + 3] = bf2f(v.w);
  }
  for (int f = tid; f < NL_ * 256; f += 512) wo[f] = Wout[f];
  __syncthreads();
  #pragma unroll
  for (int half = 0; half < 2; half++){
    int idx = half * 512 + tid;
    if (idx < 64 * NL_){
      int r = idx / NL_, l = idx % NL_;
      float acc = bout[l];
      #pragma unroll 8
      for (int u = 0; u < 256; u++)
        acc = fmaf(hcat[r * HSTR + u], wo[l * 256 + u], acc);
      em[(long)(m0 + r) * NL_ + l] = acc;
    }
  }
}

// ---------------------------------------------------------------- K5: CRF NLL per sequence
__global__ void k5_crf(const float* __restrict__ em, const int* __restrict__ chars,
                       const int* __restrict__ labels, const float* __restrict__ startv,
                       const float* __restrict__ endv, const float* __restrict__ trans,
                       float* __restrict__ partial){
  int b = blockIdx.x, lane = threadIdx.x;   // 64 threads (1 wave)
  const int* lab = labels + b * T_;
  const int* ch  = chars + b * T_;
  const float* e = em + (long)b * T_ * NL_;
  // --- score (parallel over t) ---
  float sc = 0.f; int cnt = 0;
  for (int t = lane; t < T_; t += 64){
    int m = (ch[t] != 0);
    cnt += m;
    if (m){
      sc += e[t * NL_ + lab[t]];
      if (t > 0) sc += trans[lab[t - 1] * NL_ + lab[t]];
    }
  }
  #pragma unroll
  for (int off = 32; off; off >>= 1){
    sc  += __shfl_down(sc, off);
    cnt += __shfl_down(cnt, off);
  }
  sc  = __shfl(sc, 0);
  cnt = __shfl(cnt, 0);
  if (cnt < 1) cnt = 1;
  // --- forward algorithm: lanes 0..8 hold alpha ---
  int jl = (lane < NL_) ? lane : 0;
  float tcol[NL_];
  #pragma unroll
  for (int i = 0; i < NL_; i++) tcol[i] = trans[i * NL_ + jl];
  float alpha = (lane < NL_) ? (startv[jl] + e[jl]) : -1e30f;
  for (int t = 1; t < T_; t++){
    int m = (ch[t] != 0);
    float ev = (lane < NL_) ? e[t * NL_ + jl] : 0.f;
    float vv[NL_]; float mx = -1e30f;
    #pragma unroll
    for (int i = 0; i < NL_; i++){
      vv[i] = __shfl(alpha, i) + tcol[i];
      mx = fmaxf(mx, vv[i]);
    }
    float ssum = 0.f;
    #pragma unroll
    for (int i = 0; i < NL_; i++) ssum += __expf(vv[i] - mx);
    float nxt = mx + __logf(ssum) + ev;
    if (m && lane < NL_) alpha = nxt;
  }
  float av = (lane < NL_) ? (alpha + endv[jl]) : -1e30f;
  float mx = av;
  #pragma unroll
  for (int off = 8; off; off >>= 1) mx = fmaxf(mx, __shfl_down(mx, off));
  mx = __shfl(mx, 0);
  float ex = (lane < NL_) ? __expf(av - mx) : 0.f;
  #pragma unroll
  for (int off = 8; off; off >>= 1) ex += __shfl_down(ex, off);
  if (lane == 0){
    float logZ = mx + __logf(ex);
    float score = sc + startv[lab[0]] + endv[lab[cnt - 1]];
    partial[b] = logZ - score;
  }
}

// ---------------------------------------------------------------- K6: deterministic final reduce
__global__ void k6_reduce(const float* __restrict__ partial, float* __restrict__ out){
  int lane = threadIdx.x;  // 128 threads
  float v = partial[lane];
  #pragma unroll
  for (int off = 32; off; off >>= 1) v += __shfl_down(v, off);
  __shared__ float tmp[2];
  if ((lane & 63) == 0) tmp[lane >> 6] = v;
  __syncthreads();
  if (lane == 0) out[0] = tmp[0] + tmp[1];
}

// ---------------------------------------------------------------- launch
extern "C" void kernel_launch(void* const* d_in, const int* in_sizes, int n_in,
                              void* d_out, int out_size, void* d_ws, size_t ws_size,
                              hipStream_t stream){
  const int*   chars  = (const int*)d_in[0];
  const int*   labels = (const int*)d_in[1];
  const float* emb    = (const float*)d_in[2];
  const float* Wihf   = (const float*)d_in[3];
  const float* Whhf   = (const float*)d_in[4];
  const float* bihf   = (const float*)d_in[5];
  const float* bhhf   = (const float*)d_in[6];
  const float* Wihb   = (const float*)d_in[7];
  const float* Whhb   = (const float*)d_in[8];
  const float* bihb   = (const float*)d_in[9];
  const float* bhhb   = (const float*)d_in[10];
  const float* Wout   = (const float*)d_in[11];
  const float* bout   = (const float*)d_in[12];
  const float* startv = (const float*)d_in[13];
  const float* endv   = (const float*)d_in[14];
  const float* trans  = (const float*)d_in[15];

  char* ws = (char*)d_ws;
  unsigned short* x     = (unsigned short*)(ws);                   // 16,777,216 B
  unsigned short* Wcat  = (unsigned short*)(ws + 16777216);        //    262,144 B
  float*          biasc = (float*)         (ws + 17039360);        //      4,096 B
  unsigned short* G     = (unsigned short*)(ws + 17043456);        // 134,217,728 B
  unsigned short* hs    = (unsigned short*)(ws + 151261184);       //  33,554,432 B
  float*          em    = (float*)         (ws + 184815616);       //   2,359,296 B
  float*          part  = (float*)         (ws + 187174912);       //        512 B

  hipLaunchKernelGGL(k0_prep,  dim3(1024),     dim3(128), 0, stream,
                     Wihf, Wihb, bihf, bhhf, bihb, bhhb, Wcat, biasc);
  hipLaunchKernelGGL(k1_embed, dim3(8192),     dim3(256), 0, stream, chars, emb, x);
  hipLaunchKernelGGL(k2_gemm,  dim3(1024, 8),  dim3(256), 0, stream, x, Wcat, biasc, G);
  hipLaunchKernelGGL(k3_scan,  dim3(256),      dim3(512), 0, stream, G, Whhf, Whhb, hs);
  hipLaunchKernelGGL(k4_emis,  dim3(1024),     dim3(512), 0, stream, hs, Wout, bout, em);
  hipLaunchKernelGGL(k5_crf,   dim3(128),      dim3(64),  0, stream,
                     em, chars, labels, startv, endv, trans, part);
  hipLaunchKernelGGL(k6_reduce, dim3(1),       dim3(128), 0, stream, part, (float*)d_out);
}